// Round 7
// baseline (227.456 us; speedup 1.0000x reference)
//
#include <hip/hip_runtime.h>
#include <cfloat>
#include <math.h>

#define BINS 64
#define NELEM (192*224*192)       // 8,257,536 per batch sample (C=1)
#define N4    (NELEM/4)           // 2,064,384 float4 per slice
#define NB 2
#define HIST_OFF 16               // ws u32 index where histograms start
#define BLK 256

typedef float f32x4 __attribute__((ext_vector_type(4)));

__device__ __forceinline__ f32x4 ntload(const f32x4* p){
    return __builtin_nontemporal_load(p);
}

// ws layout (u32): [0..7]  minmax keys: b*4 + {fmin,fmax,wmin,wmax}
//                  [16..16+NB*4096) joint histograms

__device__ __forceinline__ unsigned fkey(float f){
    unsigned u = __float_as_uint(f);
    return (u & 0x80000000u) ? ~u : (u | 0x80000000u);
}
__device__ __forceinline__ float funkey(unsigned k){
    unsigned u = (k & 0x80000000u) ? (k ^ 0x80000000u) : ~k;
    return __uint_as_float(u);
}

__global__ void k_init(unsigned* ws){
    int i = blockIdx.x * 256 + threadIdx.x;
    if (i < 16) ws[i] = ((i < 8) && ((i & 1) == 0)) ? 0xFFFFFFFFu : 0u;
    if (i < NB * BINS * BINS) ws[HIST_OFF + i] = 0u;
}

// grid (512, NB): y = batch. EXACT R1 structure (3.4 TB/s champion) + NT loads.
__global__ void k_minmax(const float* __restrict__ F, const float* __restrict__ W,
                         unsigned* ws){
    const int b = blockIdx.y;
    const f32x4* F4 = (const f32x4*)(F + (size_t)b * NELEM);
    const f32x4* W4 = (const f32x4*)(W + (size_t)b * NELEM);
    float fmn = FLT_MAX, fmx = -FLT_MAX, wmn = FLT_MAX, wmx = -FLT_MAX;
    for (int i = blockIdx.x * blockDim.x + threadIdx.x; i < N4;
         i += gridDim.x * blockDim.x){
        f32x4 a = ntload(F4 + i);
        f32x4 c = ntload(W4 + i);
        fmn = fminf(fmn, fminf(fminf(a[0], a[1]), fminf(a[2], a[3])));
        fmx = fmaxf(fmx, fmaxf(fmaxf(a[0], a[1]), fmaxf(a[2], a[3])));
        wmn = fminf(wmn, fminf(fminf(c[0], c[1]), fminf(c[2], c[3])));
        wmx = fmaxf(wmx, fmaxf(fmaxf(c[0], c[1]), fmaxf(c[2], c[3])));
    }
    for (int off = 32; off; off >>= 1){
        fmn = fminf(fmn, __shfl_down(fmn, off));
        fmx = fmaxf(fmx, __shfl_down(fmx, off));
        wmn = fminf(wmn, __shfl_down(wmn, off));
        wmx = fmaxf(wmx, __shfl_down(wmx, off));
    }
    __shared__ float s[4][4];
    int wave = threadIdx.x >> 6;
    if ((threadIdx.x & 63) == 0){
        s[wave][0] = fmn; s[wave][1] = fmx; s[wave][2] = wmn; s[wave][3] = wmx;
    }
    __syncthreads();
    if (threadIdx.x == 0){
        float a0 = s[0][0], a1 = s[0][1], a2 = s[0][2], a3 = s[0][3];
        for (int wv = 1; wv < 4; ++wv){
            a0 = fminf(a0, s[wv][0]); a1 = fmaxf(a1, s[wv][1]);
            a2 = fminf(a2, s[wv][2]); a3 = fmaxf(a3, s[wv][3]);
        }
        atomicMin(&ws[b*4+0], fkey(a0));
        atomicMax(&ws[b*4+1], fkey(a1));
        atomicMin(&ws[b*4+2], fkey(a2));
        atomicMax(&ws[b*4+3], fkey(a3));
    }
}

// grid (256, NB): y = batch. EXACT R1 structure + NT loads.
__global__ void k_hist(const float* __restrict__ F, const float* __restrict__ W,
                       unsigned* ws){
    const int b = blockIdx.y;
    __shared__ unsigned h[BINS * BINS];
    for (int i = threadIdx.x; i < BINS * BINS; i += blockDim.x) h[i] = 0u;
    __syncthreads();
    const float fmn = funkey(ws[b*4+0]);
    const float fmx = funkey(ws[b*4+1]);
    const float wmn = funkey(ws[b*4+2]);
    const float wmx = funkey(ws[b*4+3]);
    const float fden = fmx - fmn + 1e-10f;   // exact ref f32 arithmetic
    const float wden = wmx - wmn + 1e-10f;
    const f32x4* F4 = (const f32x4*)(F + (size_t)b * NELEM);
    const f32x4* W4 = (const f32x4*)(W + (size_t)b * NELEM);
    for (int i = blockIdx.x * blockDim.x + threadIdx.x; i < N4;
         i += gridDim.x * blockDim.x){
        f32x4 a = ntload(F4 + i);
        f32x4 c = ntload(W4 + i);
        #pragma unroll
        for (int k = 0; k < 4; ++k){
            int fi = (int)((a[k] - fmn) / fden * 63.0f);
            int wi = (int)((c[k] - wmn) / wden * 63.0f);
            fi = min(max(fi, 0), 63);
            wi = min(max(wi, 0), 63);
            atomicAdd(&h[fi * BINS + wi], 1u);
        }
    }
    __syncthreads();
    unsigned* gh = ws + HIST_OFF + b * BINS * BINS;
    for (int i = threadIdx.x; i < BINS * BINS; i += blockDim.x){
        unsigned v = h[i];
        if (v) atomicAdd(&gh[i], v);
    }
}

// 1 block x 1024: fused epilogue (joint entropy + marginals + combine + MSE)
__global__ __launch_bounds__(1024) void k_final(const float* __restrict__ pa,
                                                const float* __restrict__ ta,
                                                const unsigned* __restrict__ ws,
                                                float* __restrict__ out){
    __shared__ double sred[1024];
    __shared__ float sw[8];   // [b*2+0]=rows partial, [b*2+1]=cols partial... (4 used)
    const unsigned* hist = ws + HIST_OFF;
    const float fN = (float)NELEM;            // exact in f32 (< 2^24)
    const int t = threadIdx.x;

    // ---- marginal entropies: 256 threads, one row/col each ----
    // group g = t>>6: 0: rows b0, 1: rows b1, 2: cols b0, 3: cols b1
    float mv = 0.0f;
    if (t < 256){
        const int g = t >> 6, lane = t & 63, b = g & 1;
        unsigned c = 0;
        if (g < 2){ const unsigned* H = hist + b * 4096 + lane * 64;
            for (int j = 0; j < 64; ++j) c += H[j]; }
        else { const unsigned* H = hist + b * 4096 + lane;
            for (int j = 0; j < 64; ++j) c += H[j * 64]; }
        float p = (float)c / fN;
        mv = p * __logf(p + 1e-10f);
    }
    for (int off = 32; off; off >>= 1) mv += __shfl_down(mv, off);
    if (t < 256 && (t & 63) == 0) sw[t >> 6] = mv;

    // ---- joint entropies: all 1024 threads, 4 cells per batch each ----
    double hj[NB];
    for (int b = 0; b < NB; ++b){
        const unsigned* H = hist + b * 4096;
        double v = 0.0;
        #pragma unroll
        for (int k = 0; k < 4; ++k){
            float p = (float)H[t + k * 1024] / fN;
            v += (double)(p * __logf(p + 1e-10f));
        }
        sred[t] = v; __syncthreads();
        for (int off = 512; off; off >>= 1){
            if (t < off) sred[t] += sred[t + off];
            __syncthreads();
        }
        hj[b] = -sred[0]; __syncthreads();
    }

    if (t == 0){
        double loss_sim = 0.0;
        for (int b = 0; b < NB; ++b){
            double S  = -((double)sw[b] + (double)sw[2 + b]);   // h_f + h_w
            double mi = S - hj[b];
            double nmi = 2.0 * mi / (S + 1e-10);
            loss_sim += -nmi;
        }
        loss_sim /= (double)NB;
        double a = 0.0;
        for (int i = 0; i < 24; ++i){
            double d = (double)pa[i] - (double)ta[i];
            a += d * d;
        }
        a /= 24.0;
        out[0] = (float)(a + loss_sim);
    }
}

extern "C" void kernel_launch(void* const* d_in, const int* in_sizes, int n_in,
                              void* d_out, int out_size, void* d_ws, size_t ws_size,
                              hipStream_t stream) {
    const float* pa = (const float*)d_in[0];
    const float* ta = (const float*)d_in[1];
    const float* F  = (const float*)d_in[2];
    const float* W  = (const float*)d_in[3];
    float* out = (float*)d_out;
    unsigned* ws = (unsigned*)d_ws;

    k_init<<<33, 256, 0, stream>>>(ws);
    k_minmax<<<dim3(512, NB), BLK, 0, stream>>>(F, W, ws);
    k_hist<<<dim3(256, NB), BLK, 0, stream>>>(F, W, ws);
    k_final<<<1, 1024, 0, stream>>>(pa, ta, ws, out);
}